// Round 1
// baseline (391.399 us; speedup 1.0000x reference)
//
#include <hip/hip_runtime.h>

typedef unsigned short ushort_t;
typedef unsigned int uint_t;
typedef __attribute__((ext_vector_type(8))) short bf16x8;
typedef __attribute__((ext_vector_type(4))) float f32x4;

#define NMAT 16
#define MSZ 16384  // 128*128

__device__ __forceinline__ ushort_t f32_bf16(float f) {
  uint_t u = __builtin_bit_cast(uint_t, f);
  u += 0x7FFFu + ((u >> 16) & 1u);   // round-to-nearest-even
  return (ushort_t)(u >> 16);
}

// XOR swizzle on 16B granules: row r, elem k of a 128x128 bf16 tile.
// start bank group = 4*(((k>>3) ^ (r&7)) & 7) -> 2-way max aliasing (free, m136)
__device__ __forceinline__ int swz(int r, int k) {
  return r * 128 + (((k >> 3) ^ (r & 7)) << 3) + (k & 7);
}

// ---------------------------------------------------------------- skew/scale
__global__ void skew_kernel(const float* __restrict__ prim, float* __restrict__ B) {
  int kmat = blockIdx.x >> 6;
  int e = ((blockIdx.x & 63) << 8) + threadIdx.x;  // 0..16383
  int i = e >> 7, j = e & 127;
  const float* p = prim + kmat * MSZ;
  B[kmat * MSZ + e] = (p[i * 128 + j] - p[j * 128 + i]) * (1.0f / 128.0f);
}

// ---------------------------------------------------------------- lincomb
// Q = cI*I + c1*B + c2*B2 + c3*B3 + c4*B4
__global__ void lincomb_kernel(const float* __restrict__ B, const float* __restrict__ B2,
                               const float* __restrict__ B3, const float* __restrict__ B4,
                               float* __restrict__ Q,
                               float cI, float c1, float c2, float c3, float c4) {
  int kmat = blockIdx.x >> 6;
  int e = ((blockIdx.x & 63) << 8) + threadIdx.x;
  int idx = kmat * MSZ + e;
  int r = e >> 7, cc = e & 127;
  float v = c1 * B[idx] + c2 * B2[idx] + c3 * B3[idx] + c4 * B4[idx];
  if (r == cc) v += cI;
  Q[idx] = v;
}

// ---------------------------------------------------------------- batched f32 matmul
// C = A*Bm + e0*E0 + e1*E1 + e2*E2 + eI*I   (E's nullable)
// mode 1: instead of C, write bf16 PN (row-major) and PT (transposed)
__global__ __launch_bounds__(256) void mm_f32(
    const float* __restrict__ A, const float* __restrict__ Bm, float* __restrict__ C,
    const float* __restrict__ E0, const float* __restrict__ E1, const float* __restrict__ E2,
    float e0, float e1, float e2, float eI,
    ushort_t* __restrict__ PN, ushort_t* __restrict__ PT, int mode) {
  int bat = blockIdx.x >> 4;
  int tile = blockIdx.x & 15;
  int tr = tile >> 2, tc = tile & 3;  // 32x32 tiles in 4x4 grid
  const float* Ab = A + bat * MSZ;
  const float* Bb = Bm + bat * MSZ;
  __shared__ float As[32][33];
  __shared__ float Bs[32][33];
  int t = threadIdx.x;
  int colL = t & 31;
  int rowG = t >> 5;  // 0..7, covers rows rowG*4..rowG*4+3
  float acc[4] = {0.f, 0.f, 0.f, 0.f};
  for (int kk = 0; kk < 128; kk += 32) {
#pragma unroll
    for (int i = 0; i < 4; i++) {
      int q = t + 256 * i;
      int rr = q >> 5, cc = q & 31;
      As[rr][cc] = Ab[(tr * 32 + rr) * 128 + kk + cc];
      Bs[rr][cc] = Bb[(kk + rr) * 128 + tc * 32 + cc];
    }
    __syncthreads();
#pragma unroll
    for (int k2 = 0; k2 < 32; k2++) {
      float bv = Bs[k2][colL];
#pragma unroll
      for (int i = 0; i < 4; i++) acc[i] += As[rowG * 4 + i][k2] * bv;
    }
    __syncthreads();
  }
#pragma unroll
  for (int i = 0; i < 4; i++) {
    int r = tr * 32 + rowG * 4 + i;
    int c = tc * 32 + colL;
    int idx = bat * MSZ + r * 128 + c;
    float v = acc[i];
    if (E0) v += e0 * E0[idx];
    if (E1) v += e1 * E1[idx];
    if (E2) v += e2 * E2[idx];
    if (r == c) v += eI;
    if (mode == 0) {
      C[idx] = v;
    } else {
      ushort_t b = f32_bf16(v);
      PN[idx] = b;
      PT[bat * MSZ + c * 128 + r] = b;
    }
  }
}

// ---------------------------------------------------------------- steps
__global__ void steps_kernel(const int* __restrict__ pos, float* __restrict__ os, int N) {
  int i = blockIdx.x, j = threadIdx.x;
  int mi = pos[i] + 1, mj = pos[j] + 1;
  int di = 31 - __builtin_clz((unsigned)mi);
  int dj = 31 - __builtin_clz((unsigned)mj);
  int tt = di < dj ? di : dj;
  unsigned x = (unsigned)((mi >> (di - tt)) ^ (mj >> (dj - tt)));
  int cpl = tt - (x ? (32 - __builtin_clz(x)) : 0);
  os[i * N + j] = (float)(di + dj - 2 * cpl);
}

// ---------------------------------------------------------------- maps
// One workgroup per (token n, head h). Chain of <=11 MFMA 128^3 matmuls.
__global__ __launch_bounds__(256) void maps_kernel(
    const ushort_t* __restrict__ PN, const ushort_t* __restrict__ PT,
    const int* __restrict__ positions, float* __restrict__ out) {
  __shared__ ushort_t __align__(16) Mcur[128 * 128];
  __shared__ ushort_t __align__(16) Pbuf[128 * 128];
  int bx = blockIdx.x;
  int n = bx >> 3, h = bx & 7;
  int t = threadIdx.x;
  int wave = t >> 6, lane = t & 63;
  int quad = lane >> 4, l16 = lane & 15;
  int m = positions[n] + 1;
  int depth = 31 - __builtin_clz((unsigned)m);

  // init M = P[d0] (or I if depth==0)
  if (depth >= 1) {
    int d0 = (m >> (depth - 1)) & 1;
    const ushort_t* src = PN + (d0 * 8 + h) * MSZ;
#pragma unroll
    for (int i = 0; i < 8; i++) {
      int e = (i * 256 + t) * 8;
      int r = e >> 7, k = e & 127;
      uint4 v = *(const uint4*)(src + e);
      *(uint4*)(&Mcur[swz(r, k)]) = v;
    }
  } else {
    for (int i = 0; i < 64; i++) {
      int e = i * 256 + t;
      int r = e >> 7, k = e & 127;
      Mcur[swz(r, k)] = (r == k) ? (ushort_t)0x3F80 : (ushort_t)0;
    }
  }

  int r0 = (wave >> 1) * 64, c0 = (wave & 1) * 64;

  for (int s = 1; s < depth; s++) {
    int sel = (m >> (depth - 1 - s)) & 1;
    const ushort_t* psrc = PT + (sel * 8 + h) * MSZ;
#pragma unroll
    for (int i = 0; i < 8; i++) {
      int e = (i * 256 + t) * 8;
      int r = e >> 7, k = e & 127;
      uint4 v = *(const uint4*)(psrc + e);
      *(uint4*)(&Pbuf[swz(r, k)]) = v;
    }
    __syncthreads();  // Pbuf ready; Mcur ready (prev writes or staging)

    f32x4 acc[4][4];
#pragma unroll
    for (int rt = 0; rt < 4; rt++)
#pragma unroll
      for (int ct = 0; ct < 4; ct++) {
        f32x4 z = {0.f, 0.f, 0.f, 0.f};
        acc[rt][ct] = z;
      }

#pragma unroll
    for (int kt = 0; kt < 4; kt++) {
      int k = kt * 32 + quad * 8;
      bf16x8 a[4], b[4];
#pragma unroll
      for (int rt = 0; rt < 4; rt++)
        a[rt] = *(const bf16x8*)(&Mcur[swz(r0 + rt * 16 + l16, k)]);
#pragma unroll
      for (int ct = 0; ct < 4; ct++)
        b[ct] = *(const bf16x8*)(&Pbuf[swz(c0 + ct * 16 + l16, k)]);
#pragma unroll
      for (int rt = 0; rt < 4; rt++)
#pragma unroll
        for (int ct = 0; ct < 4; ct++)
          acc[rt][ct] = __builtin_amdgcn_mfma_f32_16x16x32_bf16(a[rt], b[ct], acc[rt][ct], 0, 0, 0);
    }
    __syncthreads();  // all reads of Mcur/Pbuf done

    if (s == depth - 1) {
      // final: write f32 result straight from accumulators
      float* ob = out + (size_t)(n * 8 + h) * MSZ;
#pragma unroll
      for (int rt = 0; rt < 4; rt++)
#pragma unroll
        for (int ct = 0; ct < 4; ct++)
#pragma unroll
          for (int reg = 0; reg < 4; reg++) {
            int row = r0 + rt * 16 + quad * 4 + reg;
            int col = c0 + ct * 16 + l16;
            ob[row * 128 + col] = acc[rt][ct][reg];
          }
    } else {
      // write back bf16 into Mcur (in-place safe: barrier above)
#pragma unroll
      for (int rt = 0; rt < 4; rt++)
#pragma unroll
        for (int ct = 0; ct < 4; ct++)
#pragma unroll
          for (int reg = 0; reg < 4; reg++) {
            int row = r0 + rt * 16 + quad * 4 + reg;
            int col = c0 + ct * 16 + l16;
            Mcur[swz(row, col)] = f32_bf16(acc[rt][ct][reg]);
          }
      __syncthreads();
    }
  }

  if (depth <= 1) {
    __syncthreads();
    float* ob = out + (size_t)(n * 8 + h) * MSZ;
    for (int i = 0; i < 64; i++) {
      int e = i * 256 + t;
      int r = e >> 7, k = e & 127;
      uint_t fu = ((uint_t)Mcur[swz(r, k)]) << 16;
      ob[e] = __builtin_bit_cast(float, fu);
    }
  }
}

// ---------------------------------------------------------------- launch
extern "C" void kernel_launch(void* const* d_in, const int* in_sizes, int n_in,
                              void* d_out, int out_size, void* d_ws, size_t ws_size,
                              hipStream_t stream) {
  const float* prim = (const float*)d_in[0];
  const int* positions = (const int*)d_in[1];
  int N = in_sizes[1];  // 256
  float* out = (float*)d_out;

  float* B = (float*)d_ws;
  float* B2 = B + NMAT * MSZ;
  float* B3 = B2 + NMAT * MSZ;
  float* B4 = B3 + NMAT * MSZ;
  float* T0 = B4 + NMAT * MSZ;
  float* T1 = T0 + NMAT * MSZ;
  ushort_t* PN = (ushort_t*)(T1 + NMAT * MSZ);
  ushort_t* PT = PN + NMAT * MSZ;

  // Taylor coefficients 1/k!
  const float c0 = 1.f, c1 = 1.f, c2 = 0.5f, c3 = 1.f / 6.f, c4 = 1.f / 24.f,
              c5 = 1.f / 120.f, c6 = 1.f / 720.f, c7 = 1.f / 5040.f,
              c8 = 1.f / 40320.f, c9 = 1.f / 362880.f, c10 = 1.f / 3628800.f,
              c11 = 1.f / 39916800.f, c12 = 1.f / 479001600.f,
              c13 = 1.f / 6227020800.f, c14 = 1.f / 87178291200.f,
              c15 = 1.f / 1307674368000.f, c16 = 1.f / 20922789888000.f;

  // B = (P - P^T)/128
  skew_kernel<<<NMAT * 64, 256, 0, stream>>>(prim, B);
  // powers
  mm_f32<<<NMAT * 16, 256, 0, stream>>>(B, B, B2, nullptr, nullptr, nullptr, 0, 0, 0, 0, nullptr, nullptr, 0);
  mm_f32<<<NMAT * 16, 256, 0, stream>>>(B2, B, B3, nullptr, nullptr, nullptr, 0, 0, 0, 0, nullptr, nullptr, 0);
  mm_f32<<<NMAT * 16, 256, 0, stream>>>(B2, B2, B4, nullptr, nullptr, nullptr, 0, 0, 0, 0, nullptr, nullptr, 0);
  // Paterson-Stockmeyer degree 16:
  // T0 = c12 I + c13 B + c14 B2 + c15 B3 + c16 B4
  lincomb_kernel<<<NMAT * 64, 256, 0, stream>>>(B, B2, B3, B4, T0, c12, c13, c14, c15, c16);
  // T1 = B4*T0 + (c8 I + c9 B + c10 B2 + c11 B3)
  mm_f32<<<NMAT * 16, 256, 0, stream>>>(B4, T0, T1, B, B2, B3, c9, c10, c11, c8, nullptr, nullptr, 0);
  // T0 = B4*T1 + (c4 I + c5 B + c6 B2 + c7 B3)
  mm_f32<<<NMAT * 16, 256, 0, stream>>>(B4, T1, T0, B, B2, B3, c5, c6, c7, c4, nullptr, nullptr, 0);
  // T1 = B4*T0 + (c0 I + c1 B + c2 B2 + c3 B3)  == exp(S/128)
  mm_f32<<<NMAT * 16, 256, 0, stream>>>(B4, T0, T1, B, B2, B3, c1, c2, c3, c0, nullptr, nullptr, 0);
  // 7 squarings -> exp(S); last one emits bf16 PN + PT
  mm_f32<<<NMAT * 16, 256, 0, stream>>>(T1, T1, T0, nullptr, nullptr, nullptr, 0, 0, 0, 0, nullptr, nullptr, 0);
  mm_f32<<<NMAT * 16, 256, 0, stream>>>(T0, T0, T1, nullptr, nullptr, nullptr, 0, 0, 0, 0, nullptr, nullptr, 0);
  mm_f32<<<NMAT * 16, 256, 0, stream>>>(T1, T1, T0, nullptr, nullptr, nullptr, 0, 0, 0, 0, nullptr, nullptr, 0);
  mm_f32<<<NMAT * 16, 256, 0, stream>>>(T0, T0, T1, nullptr, nullptr, nullptr, 0, 0, 0, 0, nullptr, nullptr, 0);
  mm_f32<<<NMAT * 16, 256, 0, stream>>>(T1, T1, T0, nullptr, nullptr, nullptr, 0, 0, 0, 0, nullptr, nullptr, 0);
  mm_f32<<<NMAT * 16, 256, 0, stream>>>(T0, T0, T1, nullptr, nullptr, nullptr, 0, 0, 0, 0, nullptr, nullptr, 0);
  mm_f32<<<NMAT * 16, 256, 0, stream>>>(T1, T1, T0, nullptr, nullptr, nullptr, 0, 0, 0, 0, PN, PT, 1);

  // steps output (after maps region)
  steps_kernel<<<N, N, 0, stream>>>(positions, out + (size_t)N * 8 * MSZ, N);

  // maps chains
  maps_kernel<<<N * 8, 256, 0, stream>>>(PN, PT, positions, out);
}

// Round 2
// 363.167 us; speedup vs baseline: 1.0777x; 1.0777x over previous
//
#include <hip/hip_runtime.h>

typedef unsigned short ushort_t;
typedef unsigned int uint_t;
typedef __attribute__((ext_vector_type(8))) short bf16x8;
typedef __attribute__((ext_vector_type(4))) float f32x4;

#define NMAT 16
#define MSZ 16384  // 128*128

__device__ __forceinline__ ushort_t f32_bf16(float f) {
  uint_t u = __builtin_bit_cast(uint_t, f);
  u += 0x7FFFu + ((u >> 16) & 1u);   // round-to-nearest-even
  return (ushort_t)(u >> 16);
}

// XOR swizzle on 16B granules: row r, elem k of a 128x128 bf16 tile.
// granule column = (k>>3) ^ (r&7) -> 2-way max bank aliasing (free, m136)
__device__ __forceinline__ int swz(int r, int k) {
  return r * 128 + (((k >> 3) ^ (r & 7)) << 3) + (k & 7);
}

// ---------------------------------------------------------------- skew/scale
// B = (P - P^T)/8   (s=3 scaling: exp(S) = (exp(S/8))^8)
__global__ void skew_kernel(const float* __restrict__ prim, float* __restrict__ B) {
  int kmat = blockIdx.x >> 6;
  int e = ((blockIdx.x & 63) << 8) + threadIdx.x;  // 0..16383
  int i = e >> 7, j = e & 127;
  const float* p = prim + kmat * MSZ;
  B[kmat * MSZ + e] = (p[i * 128 + j] - p[j * 128 + i]) * (1.0f / 8.0f);
}

// ---------------------------------------------------------------- lincomb
// Q = cI*I + c1*B + c2*B2 + c3*B3 + c4*B4
__global__ void lincomb_kernel(const float* __restrict__ B, const float* __restrict__ B2,
                               const float* __restrict__ B3, const float* __restrict__ B4,
                               float* __restrict__ Q,
                               float cI, float c1, float c2, float c3, float c4) {
  int kmat = blockIdx.x >> 6;
  int e = ((blockIdx.x & 63) << 8) + threadIdx.x;
  int idx = kmat * MSZ + e;
  int r = e >> 7, cc = e & 127;
  float v = c1 * B[idx] + c2 * B2[idx] + c3 * B3[idx] + c4 * B4[idx];
  if (r == cc) v += cI;
  Q[idx] = v;
}

// ---------------------------------------------------------------- batched f32 matmul
// C = A*Bm + e0*E0 + e1*E1 + e2*E2 + eI*I   (E's nullable)
// mode 1: instead of C, write bf16 PN (row-major) and PT (transposed)
__global__ __launch_bounds__(256) void mm_f32(
    const float* __restrict__ A, const float* __restrict__ Bm, float* __restrict__ C,
    const float* __restrict__ E0, const float* __restrict__ E1, const float* __restrict__ E2,
    float e0, float e1, float e2, float eI,
    ushort_t* __restrict__ PN, ushort_t* __restrict__ PT, int mode) {
  int bat = blockIdx.x >> 4;
  int tile = blockIdx.x & 15;
  int tr = tile >> 2, tc = tile & 3;  // 32x32 tiles in 4x4 grid
  const float* Ab = A + bat * MSZ;
  const float* Bb = Bm + bat * MSZ;
  __shared__ float As[32][33];
  __shared__ float Bs[32][33];
  int t = threadIdx.x;
  int colL = t & 31;
  int rowG = t >> 5;  // 0..7, covers rows rowG*4..rowG*4+3
  float acc[4] = {0.f, 0.f, 0.f, 0.f};
  for (int kk = 0; kk < 128; kk += 32) {
#pragma unroll
    for (int i = 0; i < 4; i++) {
      int q = t + 256 * i;
      int rr = q >> 5, cc = q & 31;
      As[rr][cc] = Ab[(tr * 32 + rr) * 128 + kk + cc];
      Bs[rr][cc] = Bb[(kk + rr) * 128 + tc * 32 + cc];
    }
    __syncthreads();
#pragma unroll
    for (int k2 = 0; k2 < 32; k2++) {
      float bv = Bs[k2][colL];
#pragma unroll
      for (int i = 0; i < 4; i++) acc[i] += As[rowG * 4 + i][k2] * bv;
    }
    __syncthreads();
  }
#pragma unroll
  for (int i = 0; i < 4; i++) {
    int r = tr * 32 + rowG * 4 + i;
    int c = tc * 32 + colL;
    int idx = bat * MSZ + r * 128 + c;
    float v = acc[i];
    if (E0) v += e0 * E0[idx];
    if (E1) v += e1 * E1[idx];
    if (E2) v += e2 * E2[idx];
    if (r == c) v += eI;
    if (mode == 0) {
      C[idx] = v;
    } else {
      ushort_t b = f32_bf16(v);
      PN[idx] = b;
      PT[bat * MSZ + c * 128 + r] = b;
    }
  }
}

// ---------------------------------------------------------------- steps
__global__ void steps_kernel(const int* __restrict__ pos, float* __restrict__ os, int N) {
  int i = blockIdx.x, j = threadIdx.x;
  int mi = pos[i] + 1, mj = pos[j] + 1;
  int di = 31 - __builtin_clz((unsigned)mi);
  int dj = 31 - __builtin_clz((unsigned)mj);
  int tt = di < dj ? di : dj;
  unsigned x = (unsigned)((mi >> (di - tt)) ^ (mj >> (dj - tt)));
  int cpl = tt - (x ? (32 - __builtin_clz(x)) : 0);
  os[i * N + j] = (float)(di + dj - 2 * cpl);
}

// ---------------------------------------------------------------- maps (v2)
// Transposed recurrence: L holds M row-major. Step computes
// D = P_sel^T (A, direct from global PT) x M^T (B, rows of L) = M_next^T.
// D[dr][dc] = M_next[dc][dr] -> packed ds_write_b64 at L[dc][dr..dr+3].
// Final step stores float4 straight to out.
__global__ __launch_bounds__(256) void maps_kernel(
    const ushort_t* __restrict__ PN, const ushort_t* __restrict__ PT,
    const int* __restrict__ positions, float* __restrict__ out) {
  __shared__ ushort_t __align__(16) L[128 * 128];  // 32 KB
  int bx = blockIdx.x;
  int n = bx >> 3, h = bx & 7;
  int t = threadIdx.x;
  int wave = t >> 6, lane = t & 63;
  int quad = lane >> 4, l16 = lane & 15;
  int m = positions[n] + 1;
  int depth = 31 - __builtin_clz((unsigned)m);
  float* ob = out + (size_t)(n * 8 + h) * MSZ;

  if (depth == 0) {  // maps = I
    for (int i = 0; i < 64; i++) {
      int e = i * 256 + t;
      int r = e >> 7, k = e & 127;
      ob[e] = (r == k) ? 1.0f : 0.0f;
    }
    return;
  }
  int d0 = (m >> (depth - 1)) & 1;
  if (depth == 1) {  // maps = P[d0] (bf16->f32)
    const ushort_t* src = PN + (d0 * 8 + h) * MSZ;
    for (int i = 0; i < 64; i++) {
      int e = i * 256 + t;
      uint_t fu = ((uint_t)src[e]) << 16;
      ob[e] = __builtin_bit_cast(float, fu);
    }
    return;
  }

  // init L = P[d0] row-major (swizzled)
  {
    const ushort_t* src = PN + (d0 * 8 + h) * MSZ;
#pragma unroll
    for (int i = 0; i < 8; i++) {
      int e = (i * 256 + t) * 8;
      int r = e >> 7, k = e & 127;
      uint4 v = *(const uint4*)(src + e);
      *(uint4*)(&L[swz(r, k)]) = v;
    }
  }
  __syncthreads();

  int r0 = (wave >> 1) * 64;  // D-row base (= M_next col base)
  int c0 = (wave & 1) * 64;   // D-col base (= M_next row base)

  for (int s = 1; s < depth; s++) {
    int sel = (m >> (depth - 1 - s)) & 1;
    const ushort_t* pt = PT + (sel * 8 + h) * MSZ;

    f32x4 acc[4][4];
#pragma unroll
    for (int rt = 0; rt < 4; rt++)
#pragma unroll
      for (int ct = 0; ct < 4; ct++) {
        f32x4 z = {0.f, 0.f, 0.f, 0.f};
        acc[rt][ct] = z;
      }

#pragma unroll
    for (int kt = 0; kt < 4; kt++) {
      int k = kt * 32 + quad * 8;
      bf16x8 a[4], b[4];
#pragma unroll
      for (int rt = 0; rt < 4; rt++)  // A = P^T rows, direct from global (L2-hot)
        a[rt] = *(const bf16x8*)(pt + (r0 + rt * 16 + l16) * 128 + k);
#pragma unroll
      for (int ct = 0; ct < 4; ct++)  // B = M^T cols = L rows
        b[ct] = *(const bf16x8*)(&L[swz(c0 + ct * 16 + l16, k)]);
#pragma unroll
      for (int rt = 0; rt < 4; rt++)
#pragma unroll
        for (int ct = 0; ct < 4; ct++)
          acc[rt][ct] = __builtin_amdgcn_mfma_f32_16x16x32_bf16(a[rt], b[ct], acc[rt][ct], 0, 0, 0);
    }
    __syncthreads();  // all reads of L done

    if (s == depth - 1) {
      // store M_next rows as float4: lane has D[dr..dr+3][dc] = M[dc][dr..dr+3]
#pragma unroll
      for (int rt = 0; rt < 4; rt++)
#pragma unroll
        for (int ct = 0; ct < 4; ct++) {
          int dr = r0 + rt * 16 + quad * 4;  // M col base, 4 consecutive
          int dc = c0 + ct * 16 + l16;       // M row
          f32x4 v = acc[rt][ct];
          *(f32x4*)(ob + dc * 128 + dr) = v;
        }
    } else {
      // packed bf16 writeback: L[dc][dr..dr+3]
#pragma unroll
      for (int rt = 0; rt < 4; rt++)
#pragma unroll
        for (int ct = 0; ct < 4; ct++) {
          int dr = r0 + rt * 16 + quad * 4;
          int dc = c0 + ct * 16 + l16;
          f32x4 v = acc[rt][ct];
          uint2 pk;
          pk.x = (uint_t)f32_bf16(v[0]) | ((uint_t)f32_bf16(v[1]) << 16);
          pk.y = (uint_t)f32_bf16(v[2]) | ((uint_t)f32_bf16(v[3]) << 16);
          *(uint2*)(&L[swz(dc, dr)]) = pk;
        }
      __syncthreads();  // L now M_{s+1}
    }
  }
}

// ---------------------------------------------------------------- launch
extern "C" void kernel_launch(void* const* d_in, const int* in_sizes, int n_in,
                              void* d_out, int out_size, void* d_ws, size_t ws_size,
                              hipStream_t stream) {
  const float* prim = (const float*)d_in[0];
  const int* positions = (const int*)d_in[1];
  int N = in_sizes[1];  // 256
  float* out = (float*)d_out;

  float* B = (float*)d_ws;
  float* B2 = B + NMAT * MSZ;
  float* B3 = B2 + NMAT * MSZ;
  float* B4 = B3 + NMAT * MSZ;
  float* T0 = B4 + NMAT * MSZ;
  float* T1 = T0 + NMAT * MSZ;
  ushort_t* PN = (ushort_t*)(T1 + NMAT * MSZ);
  ushort_t* PT = PN + NMAT * MSZ;

  // Taylor coefficients 1/k!
  const float c0 = 1.f, c1 = 1.f, c2 = 0.5f, c3 = 1.f / 6.f, c4 = 1.f / 24.f,
              c5 = 1.f / 120.f, c6 = 1.f / 720.f, c7 = 1.f / 5040.f,
              c8 = 1.f / 40320.f, c9 = 1.f / 362880.f, c10 = 1.f / 3628800.f,
              c11 = 1.f / 39916800.f, c12 = 1.f / 479001600.f,
              c13 = 1.f / 6227020800.f, c14 = 1.f / 87178291200.f,
              c15 = 1.f / 1307674368000.f, c16 = 1.f / 20922789888000.f;

  // steps output first (independent)
  steps_kernel<<<N, N, 0, stream>>>(positions, out + (size_t)N * 8 * MSZ, N);

  // B = (P - P^T)/8
  skew_kernel<<<NMAT * 64, 256, 0, stream>>>(prim, B);
  // powers
  mm_f32<<<NMAT * 16, 256, 0, stream>>>(B, B, B2, nullptr, nullptr, nullptr, 0, 0, 0, 0, nullptr, nullptr, 0);
  mm_f32<<<NMAT * 16, 256, 0, stream>>>(B2, B, B3, nullptr, nullptr, nullptr, 0, 0, 0, 0, nullptr, nullptr, 0);
  mm_f32<<<NMAT * 16, 256, 0, stream>>>(B2, B2, B4, nullptr, nullptr, nullptr, 0, 0, 0, 0, nullptr, nullptr, 0);
  // Paterson-Stockmeyer degree 16:
  lincomb_kernel<<<NMAT * 64, 256, 0, stream>>>(B, B2, B3, B4, T0, c12, c13, c14, c15, c16);
  mm_f32<<<NMAT * 16, 256, 0, stream>>>(B4, T0, T1, B, B2, B3, c9, c10, c11, c8, nullptr, nullptr, 0);
  mm_f32<<<NMAT * 16, 256, 0, stream>>>(B4, T1, T0, B, B2, B3, c5, c6, c7, c4, nullptr, nullptr, 0);
  mm_f32<<<NMAT * 16, 256, 0, stream>>>(B4, T0, T1, B, B2, B3, c1, c2, c3, c0, nullptr, nullptr, 0);
  // 3 squarings -> exp(S); last one emits bf16 PN + PT
  mm_f32<<<NMAT * 16, 256, 0, stream>>>(T1, T1, T0, nullptr, nullptr, nullptr, 0, 0, 0, 0, nullptr, nullptr, 0);
  mm_f32<<<NMAT * 16, 256, 0, stream>>>(T0, T0, T1, nullptr, nullptr, nullptr, 0, 0, 0, 0, nullptr, nullptr, 0);
  mm_f32<<<NMAT * 16, 256, 0, stream>>>(T1, T1, T0, nullptr, nullptr, nullptr, 0, 0, 0, 0, PN, PT, 1);

  // maps chains
  maps_kernel<<<N * 8, 256, 0, stream>>>(PN, PT, positions, out);
}

// Round 3
// 252.321 us; speedup vs baseline: 1.5512x; 1.4393x over previous
//
#include <hip/hip_runtime.h>

typedef unsigned short ushort_t;
typedef unsigned int uint_t;
typedef __attribute__((ext_vector_type(8))) short bf16x8;
typedef __attribute__((ext_vector_type(4))) float f32x4;

#define NMAT 16
#define MSZ 16384  // 128*128

__device__ __forceinline__ ushort_t f32_bf16(float f) {
  uint_t u = __builtin_bit_cast(uint_t, f);
  u += 0x7FFFu + ((u >> 16) & 1u);  // round-to-nearest-even
  return (ushort_t)(u >> 16);
}

__device__ __forceinline__ float bf16_f32(ushort_t b) {
  uint_t u = ((uint_t)b) << 16;
  return __builtin_bit_cast(float, u);
}

// XOR swizzle on 16B granules: row r, elem k of a 128x128 bf16 tile.
// 2-way max bank aliasing (free, m136). 8-elem granules stay contiguous.
__device__ __forceinline__ int swz(int r, int k) {
  return r * 128 + (((k >> 3) ^ (r & 7)) << 3) + (k & 7);
}

// Verified primitive (maps v2 passed): a-frags from rows of U, b-frags from
// rows of V compute D[r][c] = sum_k U[r][k]*V[c][k] = U * V^T.
// Lane (quad,l16), tile (rt,ct) holds D[dr..dr+3][dc], dr=r0+rt*16+quad*4,
// dc=c0+ct*16+l16. Packed store of D^T row-major: dst[dc][dr..dr+3].
__device__ __forceinline__ void mm_frag(const ushort_t* U, const ushort_t* V,
                                        int r0, int c0, int quad, int l16,
                                        f32x4 (&acc)[4][4]) {
#pragma unroll
  for (int rt = 0; rt < 4; rt++)
#pragma unroll
    for (int ct = 0; ct < 4; ct++) {
      f32x4 z = {0.f, 0.f, 0.f, 0.f};
      acc[rt][ct] = z;
    }
#pragma unroll
  for (int kt = 0; kt < 4; kt++) {
    int k = kt * 32 + quad * 8;
    bf16x8 a[4], b[4];
#pragma unroll
    for (int rt = 0; rt < 4; rt++) a[rt] = *(const bf16x8*)(&U[swz(r0 + rt * 16 + l16, k)]);
#pragma unroll
    for (int ct = 0; ct < 4; ct++) b[ct] = *(const bf16x8*)(&V[swz(c0 + ct * 16 + l16, k)]);
#pragma unroll
    for (int rt = 0; rt < 4; rt++)
#pragma unroll
      for (int ct = 0; ct < 4; ct++)
        acc[rt][ct] = __builtin_amdgcn_mfma_f32_16x16x32_bf16(a[rt], b[ct], acc[rt][ct], 0, 0, 0);
  }
}

// store (scale*D + cdiag*I)^T row-major, packed b64 per tile
__device__ __forceinline__ void store_T(ushort_t* dst, const f32x4 (&acc)[4][4],
                                        int r0, int c0, int quad, int l16,
                                        float scale, float cdiag) {
#pragma unroll
  for (int rt = 0; rt < 4; rt++)
#pragma unroll
    for (int ct = 0; ct < 4; ct++) {
      int dr = r0 + rt * 16 + quad * 4, dc = c0 + ct * 16 + l16;
      float v[4];
#pragma unroll
      for (int i = 0; i < 4; i++) {
        v[i] = scale * acc[rt][ct][i];
        if (dr + i == dc) v[i] += cdiag;
      }
      uint2 pk;
      pk.x = (uint_t)f32_bf16(v[0]) | ((uint_t)f32_bf16(v[1]) << 16);
      pk.y = (uint_t)f32_bf16(v[2]) | ((uint_t)f32_bf16(v[3]) << 16);
      *(uint2*)(&dst[swz(dc, dr)]) = pk;
    }
}

__device__ __forceinline__ void set_ident(ushort_t* dst, int t, float c) {
  ushort_t cb = f32_bf16(c);
  for (int i = 0; i < 64; i++) {
    int e = i * 256 + t;
    int r = e >> 7, k = e & 127;
    dst[swz(r, k)] = (r == k) ? cb : (ushort_t)0;
  }
}

// ---------------------------------------------------------------- expm part 1
// block = 2*kmat + which. X=(p-p^T)/8 (s=3 scaling). Y=X^2 symmetric.
// which=0: C(Y)=sum 1/(2k)! Y^k ; which=1: S(Y)=sum 1/(2k+1)! Y^k (Horner, deg 8).
// All iterates are poly(Y): symmetric, commute with Y -> transpose-store == store.
__global__ __launch_bounds__(256, 1) void expm1_kernel(const float* __restrict__ prim,
                                                       ushort_t* __restrict__ wsCS) {
  __shared__ ushort_t __align__(16) bufA[MSZ];
  __shared__ ushort_t __align__(16) bufB[MSZ];
  int kmat = blockIdx.x >> 1, which = blockIdx.x & 1;
  int t = threadIdx.x, wave = t >> 6, lane = t & 63;
  int quad = lane >> 4, l16 = lane & 15;
  int r0 = (wave >> 1) * 64, c0 = (wave & 1) * 64;
  const float* p = prim + kmat * MSZ;

  // stage X -> bufA
  for (int i = 0; i < 64; i++) {
    int e = i * 256 + t;
    int r = e >> 7, c = e & 127;
    bufA[swz(r, c)] = f32_bf16((p[r * 128 + c] - p[c * 128 + r]) * 0.125f);
  }
  __syncthreads();

  f32x4 acc[4][4];
  // Y = X^2 = -(X * X^T) -> bufB (symmetric)
  mm_frag(bufA, bufA, r0, c0, quad, l16, acc);
  __syncthreads();
  store_T(bufB, acc, r0, c0, quad, l16, -1.f, 0.f);
  __syncthreads();

  float coef[9];
  if (which == 0) {
    coef[0] = 1.f; coef[1] = 1.f / 2; coef[2] = 1.f / 24; coef[3] = 1.f / 720;
    coef[4] = 1.f / 40320; coef[5] = 1.f / 3628800.f; coef[6] = 1.f / 479001600.f;
    coef[7] = 1.f / 87178291200.f; coef[8] = 1.f / 20922789888000.f;
  } else {
    coef[0] = 1.f; coef[1] = 1.f / 6; coef[2] = 1.f / 120; coef[3] = 1.f / 5040;
    coef[4] = 1.f / 362880.f; coef[5] = 1.f / 39916800.f; coef[6] = 1.f / 6227020800.f;
    coef[7] = 1.f / 1307674368000.f; coef[8] = 1.f / 355687428096000.f;
  }
  // Horner in bufA (in-place; pre/post store barriers)
  set_ident(bufA, t, coef[8]);
  __syncthreads();
#pragma unroll
  for (int k = 7; k >= 0; k--) {
    mm_frag(bufB, bufA, r0, c0, quad, l16, acc);
    __syncthreads();
    store_T(bufA, acc, r0, c0, quad, l16, 1.f, coef[k]);
    __syncthreads();
  }
  // emit row-major (unswizzled granule copy)
  ushort_t* dst = wsCS + (size_t)(which * NMAT + kmat) * MSZ;
  for (int i = 0; i < 8; i++) {
    int e = (i * 256 + t) * 8;
    int r = e >> 7, k = e & 127;
    *(uint4*)(dst + e) = *(const uint4*)(&bufA[swz(r, k)]);
  }
}

// ---------------------------------------------------------------- expm part 2
// F = X*S (antisymmetric). E = C + F, E^T = C - F (C symmetric, F anti):
// EN[dc][dr+i] = C - F_i ; ET[dc][dr+i] = C + F_i  -- both packed.
// Then 3 squarings in place: D = EN * ET^T = E*E; GN scalar, GT packed.
__global__ __launch_bounds__(256, 1) void expm2_kernel(
    const float* __restrict__ prim, const ushort_t* __restrict__ wsCS,
    ushort_t* __restrict__ PN, ushort_t* __restrict__ PT) {
  __shared__ ushort_t __align__(16) bufA[MSZ];  // X -> EN/GN (row-major E)
  __shared__ ushort_t __align__(16) bufB[MSZ];  // S -> ET/GT (row-major E^T)
  int kmat = blockIdx.x;
  int t = threadIdx.x, wave = t >> 6, lane = t & 63;
  int quad = lane >> 4, l16 = lane & 15;
  int r0 = (wave >> 1) * 64, c0 = (wave & 1) * 64;
  const float* p = prim + kmat * MSZ;
  const ushort_t* Cg = wsCS + (size_t)kmat * MSZ;
  const ushort_t* Sg = wsCS + (size_t)(NMAT + kmat) * MSZ;

  for (int i = 0; i < 64; i++) {
    int e = i * 256 + t;
    int r = e >> 7, c = e & 127;
    bufA[swz(r, c)] = f32_bf16((p[r * 128 + c] - p[c * 128 + r]) * 0.125f);
  }
  for (int i = 0; i < 8; i++) {
    int e = (i * 256 + t) * 8;
    int r = e >> 7, k = e & 127;
    *(uint4*)(&bufB[swz(r, k)]) = *(const uint4*)(Sg + e);
  }
  __syncthreads();

  f32x4 acc[4][4];
  mm_frag(bufA, bufB, r0, c0, quad, l16, acc);  // F = X * S^T = X*S
  __syncthreads();
#pragma unroll
  for (int rt = 0; rt < 4; rt++)
#pragma unroll
    for (int ct = 0; ct < 4; ct++) {
      int dr = r0 + rt * 16 + quad * 4, dc = c0 + ct * 16 + l16;
      uint2 cp = *(const uint2*)(Cg + dc * 128 + dr);  // C[dc][dr..dr+3]
      float cf[4] = {bf16_f32((ushort_t)(cp.x & 0xffff)), bf16_f32((ushort_t)(cp.x >> 16)),
                     bf16_f32((ushort_t)(cp.y & 0xffff)), bf16_f32((ushort_t)(cp.y >> 16))};
      uint2 en, et;
      en.x = (uint_t)f32_bf16(cf[0] - acc[rt][ct][0]) | ((uint_t)f32_bf16(cf[1] - acc[rt][ct][1]) << 16);
      en.y = (uint_t)f32_bf16(cf[2] - acc[rt][ct][2]) | ((uint_t)f32_bf16(cf[3] - acc[rt][ct][3]) << 16);
      et.x = (uint_t)f32_bf16(cf[0] + acc[rt][ct][0]) | ((uint_t)f32_bf16(cf[1] + acc[rt][ct][1]) << 16);
      et.y = (uint_t)f32_bf16(cf[2] + acc[rt][ct][2]) | ((uint_t)f32_bf16(cf[3] + acc[rt][ct][3]) << 16);
      *(uint2*)(&bufA[swz(dc, dr)]) = en;
      *(uint2*)(&bufB[swz(dc, dr)]) = et;
    }
  __syncthreads();

#pragma unroll 1
  for (int sq = 0; sq < 3; sq++) {
    mm_frag(bufA, bufB, r0, c0, quad, l16, acc);  // G = E*E
    __syncthreads();
#pragma unroll
    for (int rt = 0; rt < 4; rt++)
#pragma unroll
      for (int ct = 0; ct < 4; ct++) {
        int dr = r0 + rt * 16 + quad * 4, dc = c0 + ct * 16 + l16;
        uint2 pk;
        pk.x = (uint_t)f32_bf16(acc[rt][ct][0]) | ((uint_t)f32_bf16(acc[rt][ct][1]) << 16);
        pk.y = (uint_t)f32_bf16(acc[rt][ct][2]) | ((uint_t)f32_bf16(acc[rt][ct][3]) << 16);
        *(uint2*)(&bufB[swz(dc, dr)]) = pk;  // G^T row-major
#pragma unroll
        for (int i = 0; i < 4; i++) bufA[swz(dr + i, dc)] = f32_bf16(acc[rt][ct][i]);  // G row-major
      }
    __syncthreads();
  }
  // emit PN (=P row-major), PT (=P^T row-major)
  for (int i = 0; i < 8; i++) {
    int e = (i * 256 + t) * 8;
    int r = e >> 7, k = e & 127;
    *(uint4*)(PN + (size_t)kmat * MSZ + e) = *(const uint4*)(&bufA[swz(r, k)]);
    *(uint4*)(PT + (size_t)kmat * MSZ + e) = *(const uint4*)(&bufB[swz(r, k)]);
  }
}

// ---------------------------------------------------------------- steps
__global__ void steps_kernel(const int* __restrict__ pos, float* __restrict__ os, int N) {
  int i = blockIdx.x, j = threadIdx.x;
  int mi = pos[i] + 1, mj = pos[j] + 1;
  int di = 31 - __builtin_clz((unsigned)mi);
  int dj = 31 - __builtin_clz((unsigned)mj);
  int tt = di < dj ? di : dj;
  unsigned x = (unsigned)((mi >> (di - tt)) ^ (mj >> (dj - tt)));
  int cpl = tt - (x ? (32 - __builtin_clz(x)) : 0);
  os[i * N + j] = (float)(di + dj - 2 * cpl);
}

// ---------------------------------------------------------------- maps (v3)
// Register-resident A: both P0^T, P1^T fragments preloaded (128 VGPRs).
// M double-buffered in LDS -> one barrier per step, zero per-step global traffic.
#define STEP_BODY(A)                                                                    \
  _Pragma("unroll") for (int kt = 0; kt < 4; kt++) {                                    \
    int k = kt * 32 + quad * 8;                                                         \
    bf16x8 b[4];                                                                        \
    _Pragma("unroll") for (int ct = 0; ct < 4; ct++)                                    \
        b[ct] = *(const bf16x8*)(&Lr[swz(c0 + ct * 16 + l16, k)]);                      \
    _Pragma("unroll") for (int rt = 0; rt < 4; rt++)                                    \
        _Pragma("unroll") for (int ct = 0; ct < 4; ct++)                                \
            acc[rt][ct] = __builtin_amdgcn_mfma_f32_16x16x32_bf16(A[kt][rt], b[ct],     \
                                                                  acc[rt][ct], 0, 0, 0); \
  }

__global__ __launch_bounds__(256, 2) void maps_kernel(
    const ushort_t* __restrict__ PN, const ushort_t* __restrict__ PT,
    const int* __restrict__ positions, float* __restrict__ out) {
  __shared__ ushort_t __align__(16) Mb[2][MSZ];  // 64 KB
  int bx = blockIdx.x;
  int n = bx >> 3, h = bx & 7;
  int t = threadIdx.x, wave = t >> 6, lane = t & 63;
  int quad = lane >> 4, l16 = lane & 15;
  int m = positions[n] + 1;
  int depth = 31 - __builtin_clz((unsigned)m);
  float* ob = out + (size_t)(n * 8 + h) * MSZ;

  if (depth == 0) {
    for (int i = 0; i < 64; i++) {
      int e = i * 256 + t;
      int r = e >> 7, k = e & 127;
      ob[e] = (r == k) ? 1.0f : 0.0f;
    }
    return;
  }
  int d0 = (m >> (depth - 1)) & 1;
  if (depth == 1) {
    const ushort_t* src = PN + (size_t)(d0 * 8 + h) * MSZ;
    for (int i = 0; i < 64; i++) {
      int e = i * 256 + t;
      ob[e] = bf16_f32(src[e]);
    }
    return;
  }

  int r0 = (wave >> 1) * 64, c0 = (wave & 1) * 64;
  // preload A fragments for both branch matrices (P^T rows)
  const ushort_t* pt0 = PT + (size_t)h * MSZ;
  const ushort_t* pt1 = PT + (size_t)(8 + h) * MSZ;
  bf16x8 a0[4][4], a1[4][4];  // [kt][rt]
#pragma unroll
  for (int kt = 0; kt < 4; kt++)
#pragma unroll
    for (int rt = 0; rt < 4; rt++) {
      int off = (r0 + rt * 16 + l16) * 128 + kt * 32 + quad * 8;
      a0[kt][rt] = *(const bf16x8*)(pt0 + off);
      a1[kt][rt] = *(const bf16x8*)(pt1 + off);
    }
  // stage M0 = P[d0] row-major into Mb[0]
  {
    const ushort_t* src = PN + (size_t)(d0 * 8 + h) * MSZ;
#pragma unroll
    for (int i = 0; i < 8; i++) {
      int e = (i * 256 + t) * 8;
      int r = e >> 7, k = e & 127;
      *(uint4*)(&Mb[0][swz(r, k)]) = *(const uint4*)(src + e);
    }
  }
  __syncthreads();

  int cur = 0;
  for (int s = 1; s < depth; s++) {
    int sel = (m >> (depth - 1 - s)) & 1;
    const ushort_t* Lr = Mb[cur];
    ushort_t* Lw = Mb[cur ^ 1];
    f32x4 acc[4][4];
#pragma unroll
    for (int rt = 0; rt < 4; rt++)
#pragma unroll
      for (int ct = 0; ct < 4; ct++) {
        f32x4 z = {0.f, 0.f, 0.f, 0.f};
        acc[rt][ct] = z;
      }
    if (sel) { STEP_BODY(a1) } else { STEP_BODY(a0) }

    if (s == depth - 1) {
      // D = (M*P)^T: lane holds D[dr..+3][dc] = M_next[dc][dr..+3] -> float4 rows
#pragma unroll
      for (int rt = 0; rt < 4; rt++)
#pragma unroll
        for (int ct = 0; ct < 4; ct++) {
          int dr = r0 + rt * 16 + quad * 4;
          int dc = c0 + ct * 16 + l16;
          *(f32x4*)(ob + dc * 128 + dr) = acc[rt][ct];
        }
    } else {
      // packed bf16 writeback to other buffer (no pre-barrier needed)
#pragma unroll
      for (int rt = 0; rt < 4; rt++)
#pragma unroll
        for (int ct = 0; ct < 4; ct++) {
          int dr = r0 + rt * 16 + quad * 4;
          int dc = c0 + ct * 16 + l16;
          uint2 pk;
          pk.x = (uint_t)f32_bf16(acc[rt][ct][0]) | ((uint_t)f32_bf16(acc[rt][ct][1]) << 16);
          pk.y = (uint_t)f32_bf16(acc[rt][ct][2]) | ((uint_t)f32_bf16(acc[rt][ct][3]) << 16);
          *(uint2*)(&Lw[swz(dc, dr)]) = pk;
        }
      __syncthreads();
      cur ^= 1;
    }
  }
}

// ---------------------------------------------------------------- launch
extern "C" void kernel_launch(void* const* d_in, const int* in_sizes, int n_in,
                              void* d_out, int out_size, void* d_ws, size_t ws_size,
                              hipStream_t stream) {
  const float* prim = (const float*)d_in[0];
  const int* positions = (const int*)d_in[1];
  int N = in_sizes[1];  // 256
  float* out = (float*)d_out;

  ushort_t* wsCS = (ushort_t*)d_ws;            // 32 matrices bf16 (C then S)
  ushort_t* PN = wsCS + 2 * NMAT * MSZ;        // 16 matrices bf16
  ushort_t* PT = PN + NMAT * MSZ;              // 16 matrices bf16

  steps_kernel<<<N, N, 0, stream>>>(positions, out + (size_t)N * 8 * MSZ, N);
  expm1_kernel<<<2 * NMAT, 256, 0, stream>>>(prim, wsCS);
  expm2_kernel<<<NMAT, 256, 0, stream>>>(prim, wsCS, PN, PT);
  maps_kernel<<<N * 8, 256, 0, stream>>>(PN, PT, positions, out);
}